// Round 1
// baseline (1046.081 us; speedup 1.0000x reference)
//
#include <hip/hip_runtime.h>
#include <hip/hip_bf16.h>
#include <cstdint>
#include <cstddef>

typedef __bf16 bf16_t;
typedef __attribute__((ext_vector_type(8))) __bf16 bf16x8;
typedef __attribute__((ext_vector_type(4))) __bf16 bf16x4;
typedef __attribute__((ext_vector_type(4))) float f32x4;

#define DEV static __device__ __forceinline__

#define BATCH 32
#define SEQ 577
#define DMODEL 768
#define MROWS (BATCH * SEQ)   // 18464
#define MPAD 18560            // 145 * 128
#define NH 12
#define HDIM 32
#define EDIM 64
#define MLPD 3072
#define NPAD 640

DEV f32x4 mfma16(bf16x8 a, bf16x8 b, f32x4 c) {
    return __builtin_amdgcn_mfma_f32_16x16x32_bf16(a, b, c, 0, 0, 0);
}

DEV void gload16(const void* g, void* l) {
    __builtin_amdgcn_global_load_lds(
        (const __attribute__((address_space(1))) void*)(uintptr_t)g,
        (__attribute__((address_space(3))) void*)(uintptr_t)l,
        16, 0, 0);
}

// ---------------- weight fp32 -> bf16 conversion ----------------
__global__ __launch_bounds__(256)
void wconv_kernel(const float* __restrict__ wq, const float* __restrict__ wk,
                  const float* __restrict__ wv, const float* __restrict__ wo,
                  const float* __restrict__ w1, const float* __restrict__ w2,
                  bf16_t* __restrict__ dst)
{
    const size_t idx = ((size_t)blockIdx.x * 256 + threadIdx.x) * 4;
    const float* src;
    size_t off;
    if      (idx <  589824) { src = wq; off = idx; }
    else if (idx < 1179648) { src = wk; off = idx - 589824; }
    else if (idx < 1769472) { src = wv; off = idx - 1179648; }
    else if (idx < 2359296) { src = wo; off = idx - 1769472; }
    else if (idx < 4718592) { src = w1; off = idx - 2359296; }
    else                    { src = w2; off = idx - 4718592; }
    const f32x4 v = *(const f32x4*)&src[off];
    bf16x4 o;
#pragma unroll
    for (int u = 0; u < 4; ++u) o[u] = (bf16_t)v[u];
    *(bf16x4*)&dst[idx] = o;
}

// ---------------- lambda scalar ----------------
__global__ void lam_kernel(const float* __restrict__ lq1, const float* __restrict__ lk1,
                           const float* __restrict__ lq2, const float* __restrict__ lk2,
                           float* __restrict__ lam)
{
    const int l = threadIdx.x;
    float a = 0.f, c = 0.f;
    if (l < 32) { a = lq1[l] * lk1[l]; c = lq2[l] * lk2[l]; }
#pragma unroll
    for (int m = 1; m < 32; m <<= 1) { a += __shfl_xor(a, m); c += __shfl_xor(c, m); }
    if (l == 0) *lam = expf(a) - expf(c) + 0.2f;
}

// ---------------- layernorm (f32 in, bf16 out, zero pad rows) ----------------
__global__ __launch_bounds__(256)
void ln_kernel(const float* __restrict__ src, const float* __restrict__ g,
               const float* __restrict__ bt, bf16_t* __restrict__ dst, const int Mv)
{
    const int row = blockIdx.x;
    const int t = threadIdx.x;
    if (row >= Mv) {
        for (int i = t; i < DMODEL; i += 256) dst[(size_t)row * DMODEL + i] = (bf16_t)0.f;
        return;
    }
    const float* p = src + (size_t)row * DMODEL;
    const float v0 = p[t], v1 = p[t + 256], v2 = p[t + 512];
    float s = v0 + v1 + v2, s2 = v0 * v0 + v1 * v1 + v2 * v2;
#pragma unroll
    for (int m = 1; m < 64; m <<= 1) { s += __shfl_xor(s, m); s2 += __shfl_xor(s2, m); }
    __shared__ float red[8];
    const int w = t >> 6;
    if ((t & 63) == 0) { red[w] = s; red[4 + w] = s2; }
    __syncthreads();
    s  = red[0] + red[1] + red[2] + red[3];
    s2 = red[4] + red[5] + red[6] + red[7];
    const float mu  = s * (1.f / DMODEL);
    const float var = s2 * (1.f / DMODEL) - mu * mu;
    const float rs = rsqrtf(var + 1e-5f);
    bf16_t* d = dst + (size_t)row * DMODEL;
    d[t      ] = (bf16_t)((v0 - mu) * rs * g[t      ] + bt[t      ]);
    d[t + 256] = (bf16_t)((v1 - mu) * rs * g[t + 256] + bt[t + 256]);
    d[t + 512] = (bf16_t)((v2 - mu) * rs * g[t + 512] + bt[t + 512]);
}

// ---------------- GEMM: C[M][N] = A[M][K] * W[N][K]^T, bf16 in, fp32 acc ----------------
// EPI 0: bf16 store. 1: +resid(f32,guarded read) -> f32. 2: +bias,GELU -> bf16.
// 3: +bias +resid -> f32, store only row < Mv.
template <int EPI>
__global__ __launch_bounds__(256)
void gemm_bt(const bf16_t* __restrict__ A, const bf16_t* __restrict__ W,
             const int K, const int N, const int KT,
             bf16_t* __restrict__ outB, float* __restrict__ outF,
             const float* __restrict__ bias, const float* __restrict__ resid,
             const int Mv)
{
    __shared__ bf16_t As[128 * 64];
    __shared__ bf16_t Bs[128 * 64];
    const int t = threadIdx.x;
    const int l = t & 63, w = t >> 6;
    const int lg = l >> 4, lc = l & 15;
    const int wr = w >> 1, wc = w & 1;
    const int tileRow = blockIdx.x * 128, tileCol = blockIdx.y * 128;
    const int srow = l >> 3, scol = (l & 7) * 8;

    f32x4 acc[4][4];
#pragma unroll
    for (int i = 0; i < 4; ++i)
#pragma unroll
        for (int j = 0; j < 4; ++j) acc[i][j] = f32x4{0.f, 0.f, 0.f, 0.f};

    for (int kt = 0; kt < KT; ++kt) {
        const int k0 = kt * 64;
#pragma unroll
        for (int i = 0; i < 4; ++i) {
            const int c = w * 4 + i;
            gload16(&A[(size_t)(tileRow + c * 8 + srow) * K + k0 + scol], &As[c * 512]);
            gload16(&W[(size_t)(tileCol + c * 8 + srow) * K + k0 + scol], &Bs[c * 512]);
        }
        __syncthreads();
#pragma unroll
        for (int ks = 0; ks < 64; ks += 32) {
            bf16x8 af[4], bfv[4];
#pragma unroll
            for (int f = 0; f < 4; ++f)
                af[f] = *(const bf16x8*)&As[(wr * 64 + f * 16 + lc) * 64 + ks + 8 * lg];
#pragma unroll
            for (int f = 0; f < 4; ++f)
                bfv[f] = *(const bf16x8*)&Bs[(wc * 64 + f * 16 + lc) * 64 + ks + 8 * lg];
#pragma unroll
            for (int i = 0; i < 4; ++i)
#pragma unroll
                for (int j = 0; j < 4; ++j)
                    acc[i][j] = mfma16(af[i], bfv[j], acc[i][j]);
        }
        __syncthreads();
    }

    const int rowB = tileRow + wr * 64 + 4 * lg;
    const int colB = tileCol + wc * 64 + lc;
#pragma unroll
    for (int i = 0; i < 4; ++i) {
#pragma unroll
        for (int j = 0; j < 4; ++j) {
#pragma unroll
            for (int r = 0; r < 4; ++r) {
                const int row = rowB + i * 16 + r;
                const int col = colB + j * 16;
                float v = acc[i][j][r];
                if (EPI == 0) {
                    outB[(size_t)row * N + col] = (bf16_t)v;
                } else if (EPI == 1) {
                    const float xin = (row < Mv) ? resid[(size_t)row * N + col] : 0.f;
                    outF[(size_t)row * N + col] = v + xin;
                } else if (EPI == 2) {
                    v += bias[col];
                    v = 0.5f * v * (1.f + erff(v * 0.70710678118654752f));
                    outB[(size_t)row * N + col] = (bf16_t)v;
                } else {
                    if (row < Mv)
                        outF[(size_t)row * N + col] = v + bias[col] + resid[(size_t)row * N + col];
                }
            }
        }
    }
}

// ---------------- V transpose: v[b,n,h,e] -> vt[(b*12+h)*64+e][n] (pad n zeroed) -----
__global__ __launch_bounds__(256)
void vtrans_kernel(const bf16_t* __restrict__ v, bf16_t* __restrict__ vt)
{
    const int nt = blockIdx.x, h = blockIdx.y, b = blockIdx.z;
    const int t = threadIdx.x;
    __shared__ bf16_t T[64][72];
    {
        const int nl = t >> 2, e0 = (t & 3) * 16;
        const int n = nt * 64 + nl;
        bf16x8 a, c;
        if (n < SEQ) {
            const bf16_t* src = &v[((size_t)b * SEQ + n) * DMODEL + h * EDIM + e0];
            a = *(const bf16x8*)src;
            c = *(const bf16x8*)(src + 8);
        } else {
#pragma unroll
            for (int u = 0; u < 8; ++u) { a[u] = (bf16_t)0.f; c[u] = (bf16_t)0.f; }
        }
#pragma unroll
        for (int u = 0; u < 8; ++u) { T[e0 + u][nl] = a[u]; T[e0 + 8 + u][nl] = c[u]; }
    }
    __syncthreads();
    {
        const int e = t >> 2, n0 = (t & 3) * 16;
        bf16x8 a, c;
#pragma unroll
        for (int u = 0; u < 8; ++u) { a[u] = T[e][n0 + u]; c[u] = T[e][n0 + 8 + u]; }
        bf16_t* d = &vt[((size_t)(b * NH + h) * EDIM + e) * NPAD + nt * 64 + n0];
        *(bf16x8*)d = a;
        *(bf16x8*)(d + 8) = c;
    }
}

// ---------------- differential flash attention ----------------
// grid (qt=10, h=12, b=32), 256 threads; wave w handles q rows qt*64+w*16..+15
__global__ __launch_bounds__(256)
void attn_kernel(const bf16_t* __restrict__ qb, const bf16_t* __restrict__ kb,
                 const bf16_t* __restrict__ vtp, const float* __restrict__ lamp,
                 const float* __restrict__ subg, bf16_t* __restrict__ outp)
{
    const int qt = blockIdx.x, h = blockIdx.y, b = blockIdx.z;
    const int t = threadIdx.x, w = t >> 6, l = t & 63;
    const int lg = l >> 4, lc = l & 15;
    const float lam = *lamp;

    __shared__ bf16_t Pl[4][16 * 72];
    bf16_t* Pw = &Pl[w][0];

    const size_t mb = (size_t)b * SEQ;
    const int qr = qt * 64 + w * 16 + lc;
    const size_t qoff = (mb + qr) * DMODEL;
    const bf16x8 q0 = *(const bf16x8*)&qb[qoff + (2 * h) * HDIM + 8 * lg];
    const bf16x8 q1 = *(const bf16x8*)&qb[qoff + (2 * h + 1) * HDIM + 8 * lg];

    f32x4 O0[4], O1[4];
    float m0[4], m1[4], l0[4], l1[4];
#pragma unroll
    for (int i = 0; i < 4; ++i) {
        O0[i] = f32x4{0.f, 0.f, 0.f, 0.f};
        O1[i] = f32x4{0.f, 0.f, 0.f, 0.f};
        m0[i] = -3e38f; m1[i] = -3e38f; l0[i] = 0.f; l1[i] = 0.f;
    }

    const size_t vtb = (size_t)(b * NH + h) * EDIM * NPAD;

    for (int kt = 0; kt < 10; ++kt) {
        bf16x8 vb[4][2];
#pragma unroll
        for (int ef = 0; ef < 4; ++ef)
#pragma unroll
            for (int ks = 0; ks < 2; ++ks)
                vb[ef][ks] = *(const bf16x8*)&vtp[vtb + (size_t)(ef * 16 + lc) * NPAD
                                                  + kt * 64 + ks * 32 + 8 * lg];

        auto head = [&](const bf16x8 qf, const int kcol, float* m, float* ls, f32x4* O) {
            f32x4 s[4];
#pragma unroll
            for (int f = 0; f < 4; ++f) {
                const bf16x8 kf = *(const bf16x8*)&kb[(mb + kt * 64 + f * 16 + lc) * DMODEL
                                                      + kcol + 8 * lg];
                s[f] = mfma16(qf, kf, f32x4{0.f, 0.f, 0.f, 0.f});
            }
#pragma unroll
            for (int f = 0; f < 4; ++f) {
                const bool pad = (kt * 64 + f * 16 + lc) >= SEQ;
#pragma unroll
                for (int r = 0; r < 4; ++r)
                    s[f][r] = pad ? -3e38f : s[f][r] * 0.17677669529663687f;
            }
            float tm[4];
#pragma unroll
            for (int r = 0; r < 4; ++r)
                tm[r] = fmaxf(fmaxf(s[0][r], s[1][r]), fmaxf(s[2][r], s[3][r]));
#pragma unroll
            for (int msk = 1; msk < 16; msk <<= 1)
#pragma unroll
                for (int r = 0; r < 4; ++r) tm[r] = fmaxf(tm[r], __shfl_xor(tm[r], msk));
            float al[4], rs[4];
#pragma unroll
            for (int r = 0; r < 4; ++r) {
                const float mn = fmaxf(m[r], tm[r]);
                al[r] = __expf(m[r] - mn);
                m[r] = mn;
                rs[r] = 0.f;
            }
#pragma unroll
            for (int f = 0; f < 4; ++f)
#pragma unroll
                for (int r = 0; r < 4; ++r) {
                    const float p = __expf(s[f][r] - m[r]);
                    s[f][r] = p;
                    rs[r] += p;
                }
#pragma unroll
            for (int msk = 1; msk < 16; msk <<= 1)
#pragma unroll
                for (int r = 0; r < 4; ++r) rs[r] += __shfl_xor(rs[r], msk);
#pragma unroll
            for (int r = 0; r < 4; ++r) ls[r] = ls[r] * al[r] + rs[r];
            // P -> LDS ([q][kv] layout, bf16), wave-private
#pragma unroll
            for (int f = 0; f < 4; ++f)
#pragma unroll
                for (int r = 0; r < 4; ++r)
                    Pw[(4 * lg + r) * 72 + f * 16 + lc] = (bf16_t)s[f][r];
#pragma unroll
            for (int ef = 0; ef < 4; ++ef)
#pragma unroll
                for (int r = 0; r < 4; ++r) O[ef][r] *= al[r];
            const bf16x8 pa0 = *(const bf16x8*)&Pw[lc * 72 + 8 * lg];
            const bf16x8 pa1 = *(const bf16x8*)&Pw[lc * 72 + 32 + 8 * lg];
#pragma unroll
            for (int ef = 0; ef < 4; ++ef) {
                O[ef] = mfma16(pa0, vb[ef][0], O[ef]);
                O[ef] = mfma16(pa1, vb[ef][1], O[ef]);
            }
        };
        head(q0, (2 * h) * HDIM, m0, l0, O0);
        head(q1, (2 * h + 1) * HDIM, m1, l1, O1);
    }

    float inv0[4], inv1[4];
#pragma unroll
    for (int r = 0; r < 4; ++r) { inv0[r] = 1.f / l0[r]; inv1[r] = lam / l1[r]; }
    float comb[4][4];
    float ms[4] = {0.f, 0.f, 0.f, 0.f};
#pragma unroll
    for (int ef = 0; ef < 4; ++ef)
#pragma unroll
        for (int r = 0; r < 4; ++r) {
            const float o = O0[ef][r] * inv0[r] - O1[ef][r] * inv1[r];
            comb[ef][r] = o;
            ms[r] += o * o;
        }
#pragma unroll
    for (int msk = 1; msk < 16; msk <<= 1)
#pragma unroll
        for (int r = 0; r < 4; ++r) ms[r] += __shfl_xor(ms[r], msk);
    float sc[4];
#pragma unroll
    for (int r = 0; r < 4; ++r) sc[r] = rsqrtf(ms[r] * (1.f / EDIM) + 1e-5f) * 0.8f;
#pragma unroll
    for (int ef = 0; ef < 4; ++ef) {
        const float gv = subg[ef * 16 + lc];
#pragma unroll
        for (int r = 0; r < 4; ++r) {
            const int nq = qt * 64 + w * 16 + 4 * lg + r;
            if (nq < SEQ)
                outp[(mb + nq) * DMODEL + h * EDIM + ef * 16 + lc] =
                    (bf16_t)(comb[ef][r] * sc[r] * gv);
        }
    }
}

// ---------------- launch ----------------
extern "C" void kernel_launch(void* const* d_in, const int* in_sizes, int n_in,
                              void* d_out, int out_size, void* d_ws, size_t ws_size,
                              hipStream_t stream)
{
    const float* x    = (const float*)d_in[0];
    const float* ln1g = (const float*)d_in[1];
    const float* ln1b = (const float*)d_in[2];
    const float* wq   = (const float*)d_in[3];
    const float* wk   = (const float*)d_in[4];
    const float* wv   = (const float*)d_in[5];
    const float* wo   = (const float*)d_in[6];
    const float* lq1  = (const float*)d_in[7];
    const float* lk1  = (const float*)d_in[8];
    const float* lq2  = (const float*)d_in[9];
    const float* lk2  = (const float*)d_in[10];
    const float* subg = (const float*)d_in[11];
    const float* ln2g = (const float*)d_in[12];
    const float* ln2b = (const float*)d_in[13];
    const float* w1   = (const float*)d_in[14];
    const float* b1   = (const float*)d_in[15];
    const float* w2   = (const float*)d_in[16];
    const float* b2   = (const float*)d_in[17];

    char* ws = (char*)d_ws;
    bf16_t* wAll = (bf16_t*)ws;
    bf16_t* wqb = wAll;
    bf16_t* wkb = wAll + 589824;
    bf16_t* wvb = wAll + 1179648;
    bf16_t* wob = wAll + 1769472;
    bf16_t* w1b = wAll + 2359296;
    bf16_t* w2b = wAll + 4718592;
    ws += 7077888ull * 2;
    float* lamP = (float*)ws; ws += 256;
    bf16_t* xn  = (bf16_t*)ws; ws += (size_t)MPAD * DMODEL * 2;   // ln1, later ln2
    bf16_t* qbf = (bf16_t*)ws;                                     // h1 aliases q..vt
    bf16_t* h1  = qbf;
    ws += (size_t)MPAD * DMODEL * 2;
    bf16_t* kbf = (bf16_t*)ws; ws += (size_t)MPAD * DMODEL * 2;
    bf16_t* vbf = (bf16_t*)ws; ws += (size_t)MPAD * DMODEL * 2;
    bf16_t* vtb = (bf16_t*)ws; ws += (size_t)(BATCH * NH) * EDIM * NPAD * 2;
    bf16_t* aout = (bf16_t*)ws; ws += (size_t)MPAD * DMODEL * 2;
    float* x1   = (float*)ws;  ws += (size_t)MPAD * DMODEL * 4;

    wconv_kernel<<<6912, 256, 0, stream>>>(wq, wk, wv, wo, w1, w2, wAll);
    lam_kernel<<<1, 64, 0, stream>>>(lq1, lk1, lq2, lk2, lamP);
    ln_kernel<<<MPAD, 256, 0, stream>>>(x, ln1g, ln1b, xn, MROWS);

    dim3 g768(145, 6);
    gemm_bt<0><<<g768, 256, 0, stream>>>(xn, wqb, 768, 768, 12, qbf, nullptr, nullptr, nullptr, MROWS);
    gemm_bt<0><<<g768, 256, 0, stream>>>(xn, wkb, 768, 768, 12, kbf, nullptr, nullptr, nullptr, MROWS);
    gemm_bt<0><<<g768, 256, 0, stream>>>(xn, wvb, 768, 768, 12, vbf, nullptr, nullptr, nullptr, MROWS);

    vtrans_kernel<<<dim3(10, 12, 32), 256, 0, stream>>>(vbf, vtb);
    attn_kernel<<<dim3(10, 12, 32), 256, 0, stream>>>(qbf, kbf, vtb, lamP, subg, aout);

    gemm_bt<1><<<g768, 256, 0, stream>>>(aout, wob, 768, 768, 12, nullptr, x1, nullptr, x, MROWS);
    ln_kernel<<<MPAD, 256, 0, stream>>>(x1, ln2g, ln2b, xn, MROWS);
    gemm_bt<2><<<dim3(145, 24), 256, 0, stream>>>(xn, w1b, 768, 3072, 12, h1, nullptr, b1, nullptr, MROWS);
    gemm_bt<3><<<g768, 256, 0, stream>>>(h1, w2b, 3072, 768, 48, nullptr, (float*)d_out, b2, x1, MROWS);
}

// Round 2
// 936.425 us; speedup vs baseline: 1.1171x; 1.1171x over previous
//
#include <hip/hip_runtime.h>
#include <hip/hip_bf16.h>
#include <cstdint>
#include <cstddef>

typedef __bf16 bf16_t;
typedef __attribute__((ext_vector_type(8))) __bf16 bf16x8;
typedef __attribute__((ext_vector_type(4))) __bf16 bf16x4;
typedef __attribute__((ext_vector_type(4))) float f32x4;

#define DEV static __device__ __forceinline__

#define BATCH 32
#define SEQ 577
#define DMODEL 768
#define MROWS (BATCH * SEQ)   // 18464
#define MPAD 18560            // 145 * 128
#define NH 12
#define HDIM 32
#define EDIM 64
#define MLPD 3072
#define NPAD 640
#define QKVSTR 2304

DEV f32x4 mfma16(bf16x8 a, bf16x8 b, f32x4 c) {
    return __builtin_amdgcn_mfma_f32_16x16x32_bf16(a, b, c, 0, 0, 0);
}

DEV void gload16(const void* g, void* l) {
    __builtin_amdgcn_global_load_lds(
        (const __attribute__((address_space(1))) void*)(uintptr_t)g,
        (__attribute__((address_space(3))) void*)(uintptr_t)l,
        16, 0, 0);
}

// ---- DPP 16-lane row reductions (VALU, no LDS pipe) ----
template <int CTRL> DEV float dppmax(float x) {
    int y = __builtin_amdgcn_mov_dpp(__builtin_bit_cast(int, x), CTRL, 0xF, 0xF, true);
    return fmaxf(x, __builtin_bit_cast(float, y));
}
DEV float rowmax16(float x) {
    x = dppmax<0xB1>(x);   // quad_perm 1,0,3,2
    x = dppmax<0x4E>(x);   // quad_perm 2,3,0,1
    x = dppmax<0x141>(x);  // row_half_mirror
    x = dppmax<0x140>(x);  // row_mirror
    return x;
}
template <int CTRL> DEV float dppadd(float x) {
    int y = __builtin_amdgcn_mov_dpp(__builtin_bit_cast(int, x), CTRL, 0xF, 0xF, true);
    return x + __builtin_bit_cast(float, y);
}
DEV float rowsum16(float x) {
    x = dppadd<0xB1>(x);
    x = dppadd<0x4E>(x);
    x = dppadd<0x141>(x);
    x = dppadd<0x140>(x);
    return x;
}

// ---- bijective XCD chunking (m204) ----
DEV int xcd_swz(int orig, int nwg) {
    const int q = nwg >> 3, r = nwg & 7;
    const int xcd = orig & 7, loc = orig >> 3;
    return (xcd < r ? xcd * (q + 1) : r * (q + 1) + (xcd - r) * q) + loc;
}

// ---------------- weight fp32 -> bf16 conversion ----------------
__global__ __launch_bounds__(256)
void wconv_kernel(const float* __restrict__ wq, const float* __restrict__ wk,
                  const float* __restrict__ wv, const float* __restrict__ wo,
                  const float* __restrict__ w1, const float* __restrict__ w2,
                  bf16_t* __restrict__ dst)
{
    const size_t idx = ((size_t)blockIdx.x * 256 + threadIdx.x) * 4;
    const float* src;
    size_t off;
    if      (idx <  589824) { src = wq; off = idx; }
    else if (idx < 1179648) { src = wk; off = idx - 589824; }
    else if (idx < 1769472) { src = wv; off = idx - 1179648; }
    else if (idx < 2359296) { src = wo; off = idx - 1769472; }
    else if (idx < 4718592) { src = w1; off = idx - 2359296; }
    else                    { src = w2; off = idx - 4718592; }
    const f32x4 v = *(const f32x4*)&src[off];
    bf16x4 o;
#pragma unroll
    for (int u = 0; u < 4; ++u) o[u] = (bf16_t)v[u];
    *(bf16x4*)&dst[idx] = o;
}

// ---------------- lambda scalar ----------------
__global__ void lam_kernel(const float* __restrict__ lq1, const float* __restrict__ lk1,
                           const float* __restrict__ lq2, const float* __restrict__ lk2,
                           float* __restrict__ lam)
{
    const int l = threadIdx.x;
    float a = 0.f, c = 0.f;
    if (l < 32) { a = lq1[l] * lk1[l]; c = lq2[l] * lk2[l]; }
#pragma unroll
    for (int m = 1; m < 32; m <<= 1) { a += __shfl_xor(a, m); c += __shfl_xor(c, m); }
    if (l == 0) *lam = expf(a) - expf(c) + 0.2f;
}

// ---------------- layernorm (f32 in, bf16 out, zero pad rows) ----------------
__global__ __launch_bounds__(256)
void ln_kernel(const float* __restrict__ src, const float* __restrict__ g,
               const float* __restrict__ bt, bf16_t* __restrict__ dst, const int Mv)
{
    const int row = blockIdx.x;
    const int t = threadIdx.x;
    if (row >= Mv) {
        for (int i = t; i < DMODEL; i += 256) dst[(size_t)row * DMODEL + i] = (bf16_t)0.f;
        return;
    }
    const float* p = src + (size_t)row * DMODEL;
    const float v0 = p[t], v1 = p[t + 256], v2 = p[t + 512];
    float s = v0 + v1 + v2, s2 = v0 * v0 + v1 * v1 + v2 * v2;
#pragma unroll
    for (int m = 1; m < 64; m <<= 1) { s += __shfl_xor(s, m); s2 += __shfl_xor(s2, m); }
    __shared__ float red[8];
    const int w = t >> 6;
    if ((t & 63) == 0) { red[w] = s; red[4 + w] = s2; }
    __syncthreads();
    s  = red[0] + red[1] + red[2] + red[3];
    s2 = red[4] + red[5] + red[6] + red[7];
    const float mu  = s * (1.f / DMODEL);
    const float var = s2 * (1.f / DMODEL) - mu * mu;
    const float rs = rsqrtf(var + 1e-5f);
    bf16_t* d = dst + (size_t)row * DMODEL;
    d[t      ] = (bf16_t)((v0 - mu) * rs * g[t      ] + bt[t      ]);
    d[t + 256] = (bf16_t)((v1 - mu) * rs * g[t + 256] + bt[t + 256]);
    d[t + 512] = (bf16_t)((v2 - mu) * rs * g[t + 512] + bt[t + 512]);
}

// ---------------- GEMM: C[M][N] = A[M][K] * W[N][K]^T, bf16 in, fp32 acc ----------------
template <int EPI>
__global__ __launch_bounds__(256)
void gemm_bt(const bf16_t* __restrict__ A, const bf16_t* __restrict__ W,
             const int K, const int N, const int KT,
             bf16_t* __restrict__ outB, float* __restrict__ outF,
             const float* __restrict__ bias, const float* __restrict__ resid,
             const int Mv)
{
    __shared__ bf16_t As[128 * 64];
    __shared__ bf16_t Bs[128 * 64];
    const int t = threadIdx.x;
    const int l = t & 63, w = t >> 6;
    const int lg = l >> 4, lc = l & 15;
    const int wr = w >> 1, wc = w & 1;
    // XCD-chunked, row-panel-major: consecutive blocks in a chunk share the A panel
    const int nwg = gridDim.x * gridDim.y;
    const int orig = blockIdx.y * gridDim.x + blockIdx.x;
    const int wg = xcd_swz(orig, nwg);
    const int tileRow = (wg / gridDim.y) * 128;
    const int tileCol = (wg % gridDim.y) * 128;
    const int srow = l >> 3, scol = (l & 7) * 8;

    f32x4 acc[4][4];
#pragma unroll
    for (int i = 0; i < 4; ++i)
#pragma unroll
        for (int j = 0; j < 4; ++j) acc[i][j] = f32x4{0.f, 0.f, 0.f, 0.f};

    for (int kt = 0; kt < KT; ++kt) {
        const int k0 = kt * 64;
#pragma unroll
        for (int i = 0; i < 4; ++i) {
            const int c = w * 4 + i;
            gload16(&A[(size_t)(tileRow + c * 8 + srow) * K + k0 + scol], &As[c * 512]);
            gload16(&W[(size_t)(tileCol + c * 8 + srow) * K + k0 + scol], &Bs[c * 512]);
        }
        __syncthreads();
#pragma unroll
        for (int ks = 0; ks < 64; ks += 32) {
            bf16x8 af[4], bfv[4];
#pragma unroll
            for (int f = 0; f < 4; ++f)
                af[f] = *(const bf16x8*)&As[(wr * 64 + f * 16 + lc) * 64 + ks + 8 * lg];
#pragma unroll
            for (int f = 0; f < 4; ++f)
                bfv[f] = *(const bf16x8*)&Bs[(wc * 64 + f * 16 + lc) * 64 + ks + 8 * lg];
#pragma unroll
            for (int i = 0; i < 4; ++i)
#pragma unroll
                for (int j = 0; j < 4; ++j)
                    acc[i][j] = mfma16(af[i], bfv[j], acc[i][j]);
        }
        __syncthreads();
    }

    const int rowB = tileRow + wr * 64 + 4 * lg;
    const int colB = tileCol + wc * 64 + lc;
#pragma unroll
    for (int i = 0; i < 4; ++i) {
#pragma unroll
        for (int j = 0; j < 4; ++j) {
#pragma unroll
            for (int r = 0; r < 4; ++r) {
                const int row = rowB + i * 16 + r;
                const int col = colB + j * 16;
                float v = acc[i][j][r];
                if (EPI == 0) {
                    outB[(size_t)row * N + col] = (bf16_t)v;
                } else if (EPI == 1) {
                    const float xin = (row < Mv) ? resid[(size_t)row * N + col] : 0.f;
                    outF[(size_t)row * N + col] = v + xin;
                } else if (EPI == 2) {
                    v += bias[col];
                    v = 0.5f * v * (1.f + erff(v * 0.70710678118654752f));
                    outB[(size_t)row * N + col] = (bf16_t)v;
                } else {
                    if (row < Mv)
                        outF[(size_t)row * N + col] = v + bias[col] + resid[(size_t)row * N + col];
                }
            }
        }
    }
}

// ---------------- V transpose: qkv v-cols -> vt[(b*12+h)*64+e][n] (pad n zeroed) -----
__global__ __launch_bounds__(256)
void vtrans_kernel(const bf16_t* __restrict__ qkv, bf16_t* __restrict__ vt)
{
    const int nt = blockIdx.x, h = blockIdx.y, b = blockIdx.z;
    const int t = threadIdx.x;
    __shared__ bf16_t T[64][72];
    {
        const int nl = t >> 2, e0 = (t & 3) * 16;
        const int n = nt * 64 + nl;
        bf16x8 a, c;
        if (n < SEQ) {
            const bf16_t* src = &qkv[((size_t)b * SEQ + n) * QKVSTR + 1536 + h * EDIM + e0];
            a = *(const bf16x8*)src;
            c = *(const bf16x8*)(src + 8);
        } else {
#pragma unroll
            for (int u = 0; u < 8; ++u) { a[u] = (bf16_t)0.f; c[u] = (bf16_t)0.f; }
        }
#pragma unroll
        for (int u = 0; u < 8; ++u) { T[e0 + u][nl] = a[u]; T[e0 + 8 + u][nl] = c[u]; }
    }
    __syncthreads();
    {
        const int e = t >> 2, n0 = (t & 3) * 16;
        bf16x8 a, c;
#pragma unroll
        for (int u = 0; u < 8; ++u) { a[u] = T[e][n0 + u]; c[u] = T[e][n0 + 8 + u]; }
        bf16_t* d = &vt[((size_t)(b * NH + h) * EDIM + e) * NPAD + nt * 64 + n0];
        *(bf16x8*)d = a;
        *(bf16x8*)(d + 8) = c;
    }
}

// ---------------- differential flash attention v2 ----------------
// 4 waves/block, 128 q rows/block (32/wave), K/V LDS-staged double-buffered.
__global__ __launch_bounds__(256)
void attn_kernel(const bf16_t* __restrict__ qkv, const bf16_t* __restrict__ vtp,
                 const float* __restrict__ lamp, const float* __restrict__ subg,
                 bf16_t* __restrict__ outp)
{
    const int orig = blockIdx.x + 5 * (blockIdx.y + 12 * blockIdx.z);
    const int wg = xcd_swz(orig, 1920);
    const int qt = wg % 5;
    const int h  = (wg / 5) % 12;
    const int b  = wg / 60;
    const int t = threadIdx.x, w = t >> 6, l = t & 63;
    const int lg = l >> 4, lc = l & 15;
    const float lam = *lamp;
    const float SC = 0.17677669529663687f;  // 1/sqrt(32)

    __shared__ bf16_t Ks[2][64 * 64];
    __shared__ bf16_t Vs[2][64 * 64];
    __shared__ bf16_t Pl[4][16 * 72];
    bf16_t* Pw = &Pl[w][0];

    const size_t mb = (size_t)b * SEQ;
    const int q0row = qt * 128 + w * 32;

    bf16x8 qf[2][2];
#pragma unroll
    for (int qs = 0; qs < 2; ++qs)
#pragma unroll
        for (int hh = 0; hh < 2; ++hh)
            qf[qs][hh] = *(const bf16x8*)&qkv[(mb + q0row + qs * 16 + lc) * QKVSTR
                                              + h * 64 + hh * 32 + 8 * lg];

    f32x4 O[2][2][4];
    f32x4 Ol[2][2];
    float mx[2][2][4];
#pragma unroll
    for (int qs = 0; qs < 2; ++qs)
#pragma unroll
        for (int hh = 0; hh < 2; ++hh) {
            Ol[qs][hh] = f32x4{0.f, 0.f, 0.f, 0.f};
#pragma unroll
            for (int ef = 0; ef < 4; ++ef) O[qs][hh][ef] = f32x4{0.f, 0.f, 0.f, 0.f};
#pragma unroll
            for (int r = 0; r < 4; ++r) mx[qs][hh][r] = -3e38f;
        }

    bf16x8 ones;
#pragma unroll
    for (int u = 0; u < 8; ++u) ones[u] = (bf16_t)1.0f;

    const int lrow = l >> 3, lchunk = l & 7;

    auto stage = [&](int kt, int bufi) {
#pragma unroll
        for (int ii = 0; ii < 2; ++ii) {
            const int R = w * 16 + ii * 8;
            const int row = R + lrow;
            const int sc = (lchunk ^ (row & 7)) * 8;   // inverse-swizzled source chunk
            gload16(&qkv[(mb + kt * 64 + row) * QKVSTR + 768 + h * 64 + sc],
                    &Ks[bufi][R * 64]);
            gload16(&vtp[(size_t)((b * NH + h) * EDIM + row) * NPAD + kt * 64 + sc],
                    &Vs[bufi][R * 64]);
        }
    };

    stage(0, 0);
    int buf = 0;

#pragma unroll 1
    for (int kt = 0; kt < 10; ++kt) {
        __syncthreads();                 // staged buf ready; buf^1 free to overwrite
        if (kt < 9) stage(kt + 1, buf ^ 1);

        bf16x8 vb[4][2];
#pragma unroll
        for (int ef = 0; ef < 4; ++ef)
#pragma unroll
            for (int ks = 0; ks < 2; ++ks)
                vb[ef][ks] = *(const bf16x8*)&Vs[buf][(ef * 16 + lc) * 64
                                                      + (((ks * 4 + lg) ^ (lc & 7)) * 8)];
#pragma unroll
        for (int hh = 0; hh < 2; ++hh) {
            bf16x8 kf[4];
#pragma unroll
            for (int f = 0; f < 4; ++f)
                kf[f] = *(const bf16x8*)&Ks[buf][(f * 16 + lc) * 64
                                                 + (((hh * 4 + lg) ^ (lc & 7)) * 8)];
#pragma unroll
            for (int qs = 0; qs < 2; ++qs) {
                f32x4 s[4];
#pragma unroll
                for (int f = 0; f < 4; ++f)
                    s[f] = mfma16(qf[qs][hh], kf[f], f32x4{0.f, 0.f, 0.f, 0.f});
                if (kt == 9) {
#pragma unroll
                    for (int f = 0; f < 4; ++f) {
                        const bool pad = (f * 16 + lc) != 0;  // only k=576 valid
#pragma unroll
                        for (int r = 0; r < 4; ++r) if (pad) s[f][r] = -3e38f;
                    }
                }
                float tm[4];
#pragma unroll
                for (int r = 0; r < 4; ++r)
                    tm[r] = rowmax16(fmaxf(fmaxf(s[0][r], s[1][r]), fmaxf(s[2][r], s[3][r])));
                float* m = mx[qs][hh];
                const bool grow = (tm[0] > m[0]) | (tm[1] > m[1]) |
                                  (tm[2] > m[2]) | (tm[3] > m[3]);
                if (__ballot(grow) != 0ull) {
                    float al[4];
#pragma unroll
                    for (int r = 0; r < 4; ++r) {
                        const float mn = fmaxf(m[r], tm[r]);
                        al[r] = __expf((m[r] - mn) * SC);
                        m[r] = mn;
                    }
                    f32x4* Oc = O[qs][hh];
#pragma unroll
                    for (int ef = 0; ef < 4; ++ef)
#pragma unroll
                        for (int r = 0; r < 4; ++r) Oc[ef][r] *= al[r];
#pragma unroll
                    for (int r = 0; r < 4; ++r) Ol[qs][hh][r] *= al[r];
                }
                float mc[4];
#pragma unroll
                for (int r = 0; r < 4; ++r) mc[r] = m[r] * SC;
#pragma unroll
                for (int f = 0; f < 4; ++f)
#pragma unroll
                    for (int r = 0; r < 4; ++r) {
                        const float p = __expf(fmaf(s[f][r], SC, -mc[r]));
                        Pw[(4 * lg + r) * 72 + f * 16 + lc] = (bf16_t)p;
                    }
                const bf16x8 pa0 = *(const bf16x8*)&Pw[lc * 72 + 8 * lg];
                const bf16x8 pa1 = *(const bf16x8*)&Pw[lc * 72 + 32 + 8 * lg];
                f32x4* Oc = O[qs][hh];
#pragma unroll
                for (int ef = 0; ef < 4; ++ef) {
                    Oc[ef] = mfma16(pa0, vb[ef][0], Oc[ef]);
                    Oc[ef] = mfma16(pa1, vb[ef][1], Oc[ef]);
                }
                Ol[qs][hh] = mfma16(pa0, ones, Ol[qs][hh]);  // row-sum rides accumulator
                Ol[qs][hh] = mfma16(pa1, ones, Ol[qs][hh]);
            }
        }
        buf ^= 1;
    }

#pragma unroll
    for (int qs = 0; qs < 2; ++qs) {
        float i0[4], i1[4], comb[4][4], ms[4];
#pragma unroll
        for (int r = 0; r < 4; ++r) {
            i0[r] = 1.f / Ol[qs][0][r];
            i1[r] = lam / Ol[qs][1][r];
            ms[r] = 0.f;
        }
#pragma unroll
        for (int ef = 0; ef < 4; ++ef)
#pragma unroll
            for (int r = 0; r < 4; ++r) {
                const float o = O[qs][0][ef][r] * i0[r] - O[qs][1][ef][r] * i1[r];
                comb[ef][r] = o;
                ms[r] += o * o;
            }
#pragma unroll
        for (int r = 0; r < 4; ++r) {
            ms[r] = rowsum16(ms[r]);
            ms[r] = rsqrtf(ms[r] * (1.f / 64.f) + 1e-5f) * 0.8f;
        }
#pragma unroll
        for (int ef = 0; ef < 4; ++ef) {
            const float gv = subg[ef * 16 + lc];
#pragma unroll
            for (int r = 0; r < 4; ++r) {
                const int nq = q0row + qs * 16 + 4 * lg + r;
                if (nq < SEQ)
                    outp[(mb + nq) * DMODEL + h * EDIM + ef * 16 + lc] =
                        (bf16_t)(comb[ef][r] * ms[r] * gv);
            }
        }
    }
}

// ---------------- launch ----------------
extern "C" void kernel_launch(void* const* d_in, const int* in_sizes, int n_in,
                              void* d_out, int out_size, void* d_ws, size_t ws_size,
                              hipStream_t stream)
{
    const float* x    = (const float*)d_in[0];
    const float* ln1g = (const float*)d_in[1];
    const float* ln1b = (const float*)d_in[2];
    const float* wq   = (const float*)d_in[3];
    const float* wk   = (const float*)d_in[4];
    const float* wv   = (const float*)d_in[5];
    const float* wo   = (const float*)d_in[6];
    const float* lq1  = (const float*)d_in[7];
    const float* lk1  = (const float*)d_in[8];
    const float* lq2  = (const float*)d_in[9];
    const float* lk2  = (const float*)d_in[10];
    const float* subg = (const float*)d_in[11];
    const float* ln2g = (const float*)d_in[12];
    const float* ln2b = (const float*)d_in[13];
    const float* w1   = (const float*)d_in[14];
    const float* b1   = (const float*)d_in[15];
    const float* w2   = (const float*)d_in[16];
    const float* b2   = (const float*)d_in[17];

    char* ws = (char*)d_ws;
    bf16_t* wAll = (bf16_t*)ws;               // wq|wk|wv (fused) | wo | w1 | w2
    bf16_t* wob = wAll + 1769472;
    bf16_t* w1b = wAll + 2359296;
    bf16_t* w2b = wAll + 4718592;
    ws += 7077888ull * 2;
    float* lamP = (float*)ws; ws += 256;
    bf16_t* xn   = (bf16_t*)ws; ws += (size_t)MPAD * DMODEL * 2;
    bf16_t* qkvb = (bf16_t*)ws;               // [MPAD][2304]; h1 aliases here later
    bf16_t* h1   = qkvb;
    ws += (size_t)MPAD * QKVSTR * 2;
    bf16_t* vtb  = (bf16_t*)ws; ws += (size_t)(BATCH * NH) * EDIM * NPAD * 2;
    bf16_t* aout = (bf16_t*)ws; ws += (size_t)MPAD * DMODEL * 2;
    float* x1    = (float*)ws;  ws += (size_t)MPAD * DMODEL * 4;

    wconv_kernel<<<6912, 256, 0, stream>>>(wq, wk, wv, wo, w1, w2, wAll);
    lam_kernel<<<1, 64, 0, stream>>>(lq1, lk1, lq2, lk2, lamP);
    ln_kernel<<<MPAD, 256, 0, stream>>>(x, ln1g, ln1b, xn, MROWS);

    // fused QKV: [MPAD][768] x [2304][768]^T
    gemm_bt<0><<<dim3(145, 18), 256, 0, stream>>>(xn, wAll, 768, QKVSTR, 12,
                                                  qkvb, nullptr, nullptr, nullptr, MROWS);

    vtrans_kernel<<<dim3(10, 12, 32), 256, 0, stream>>>(qkvb, vtb);
    attn_kernel<<<dim3(5, 12, 32), 256, 0, stream>>>(qkvb, vtb, lamP, subg, aout);

    gemm_bt<1><<<dim3(145, 6), 256, 0, stream>>>(aout, wob, 768, 768, 12,
                                                 nullptr, x1, nullptr, x, MROWS);
    ln_kernel<<<MPAD, 256, 0, stream>>>(x1, ln2g, ln2b, xn, MROWS);
    gemm_bt<2><<<dim3(145, 24), 256, 0, stream>>>(xn, w1b, 768, MLPD, 12,
                                                  h1, nullptr, b1, nullptr, MROWS);
    gemm_bt<3><<<dim3(145, 6), 256, 0, stream>>>(h1, w2b, MLPD, 768, 48,
                                                 nullptr, (float*)d_out, b2, x1, MROWS);
}

// Round 3
// 790.942 us; speedup vs baseline: 1.3226x; 1.1839x over previous
//
#include <hip/hip_runtime.h>
#include <hip/hip_bf16.h>
#include <cstdint>
#include <cstddef>

typedef __bf16 bf16_t;
typedef __attribute__((ext_vector_type(8))) __bf16 bf16x8;
typedef __attribute__((ext_vector_type(4))) __bf16 bf16x4;
typedef __attribute__((ext_vector_type(4))) float f32x4;
typedef __attribute__((ext_vector_type(4))) int int4v;
typedef __attribute__((ext_vector_type(2))) unsigned uintx2;

#define DEV static __device__ __forceinline__

#define BATCH 32
#define SEQ 577
#define DMODEL 768
#define MROWS (BATCH * SEQ)   // 18464
#define MPAD 18560            // 145 * 128
#define NH 12
#define HDIM 32
#define EDIM 64
#define MLPD 3072
#define NPAD 640
#define QKVSTR 2304

DEV f32x4 mfma16(bf16x8 a, bf16x8 b, f32x4 c) {
    return __builtin_amdgcn_mfma_f32_16x16x32_bf16(a, b, c, 0, 0, 0);
}

DEV void gload16(const void* g, void* l) {
    __builtin_amdgcn_global_load_lds(
        (const __attribute__((address_space(1))) void*)(uintptr_t)g,
        (__attribute__((address_space(3))) void*)(uintptr_t)l,
        16, 0, 0);
}

DEV unsigned cvt_pk_bf16(float lo, float hi) {
    unsigned r;
    asm("v_cvt_pk_bf16_f32 %0, %1, %2" : "=v"(r) : "v"(lo), "v"(hi));
    return r;
}
// permlane swaps (gfx950): mutual exchange of 16/32-lane rows between 2 regs
DEV void plane16_swap(unsigned& a, unsigned& b) {
    asm("v_permlane16_swap_b32 %0, %1" : "+v"(a), "+v"(b));
}
DEV void plane32_swap(unsigned& a, unsigned& b) {
    asm("v_permlane32_swap_b32 %0, %1" : "+v"(a), "+v"(b));
}

// ---- bijective XCD chunking (m204) ----
DEV int xcd_swz(int orig, int nwg) {
    const int q = nwg >> 3, r = nwg & 7;
    const int xcd = orig & 7, loc = orig >> 3;
    return (xcd < r ? xcd * (q + 1) : r * (q + 1) + (xcd - r) * q) + loc;
}

// ---------------- weight fp32 -> bf16 conversion ----------------
__global__ __launch_bounds__(256)
void wconv_kernel(const float* __restrict__ wq, const float* __restrict__ wk,
                  const float* __restrict__ wv, const float* __restrict__ wo,
                  const float* __restrict__ w1, const float* __restrict__ w2,
                  bf16_t* __restrict__ dst)
{
    const size_t idx = ((size_t)blockIdx.x * 256 + threadIdx.x) * 4;
    const float* src;
    size_t off;
    if      (idx <  589824) { src = wq; off = idx; }
    else if (idx < 1179648) { src = wk; off = idx - 589824; }
    else if (idx < 1769472) { src = wv; off = idx - 1179648; }
    else if (idx < 2359296) { src = wo; off = idx - 1769472; }
    else if (idx < 4718592) { src = w1; off = idx - 2359296; }
    else                    { src = w2; off = idx - 4718592; }
    const f32x4 v = *(const f32x4*)&src[off];
    bf16x4 o;
#pragma unroll
    for (int u = 0; u < 4; ++u) o[u] = (bf16_t)v[u];
    *(bf16x4*)&dst[idx] = o;
}

// ---------------- lambda scalar ----------------
__global__ void lam_kernel(const float* __restrict__ lq1, const float* __restrict__ lk1,
                           const float* __restrict__ lq2, const float* __restrict__ lk2,
                           float* __restrict__ lam)
{
    const int l = threadIdx.x;
    float a = 0.f, c = 0.f;
    if (l < 32) { a = lq1[l] * lk1[l]; c = lq2[l] * lk2[l]; }
#pragma unroll
    for (int m = 1; m < 32; m <<= 1) { a += __shfl_xor(a, m); c += __shfl_xor(c, m); }
    if (l == 0) *lam = expf(a) - expf(c) + 0.2f;
}

// ---------------- layernorm (f32 in, bf16 out, zero pad rows) ----------------
__global__ __launch_bounds__(256)
void ln_kernel(const float* __restrict__ src, const float* __restrict__ g,
               const float* __restrict__ bt, bf16_t* __restrict__ dst, const int Mv)
{
    const int row = blockIdx.x;
    const int t = threadIdx.x;
    if (row >= Mv) {
        for (int i = t; i < DMODEL; i += 256) dst[(size_t)row * DMODEL + i] = (bf16_t)0.f;
        return;
    }
    const float* p = src + (size_t)row * DMODEL;
    const float v0 = p[t], v1 = p[t + 256], v2 = p[t + 512];
    float s = v0 + v1 + v2, s2 = v0 * v0 + v1 * v1 + v2 * v2;
#pragma unroll
    for (int m = 1; m < 64; m <<= 1) { s += __shfl_xor(s, m); s2 += __shfl_xor(s2, m); }
    __shared__ float red[8];
    const int w = t >> 6;
    if ((t & 63) == 0) { red[w] = s; red[4 + w] = s2; }
    __syncthreads();
    s  = red[0] + red[1] + red[2] + red[3];
    s2 = red[4] + red[5] + red[6] + red[7];
    const float mu  = s * (1.f / DMODEL);
    const float var = s2 * (1.f / DMODEL) - mu * mu;
    const float rs = rsqrtf(var + 1e-5f);
    bf16_t* d = dst + (size_t)row * DMODEL;
    d[t      ] = (bf16_t)((v0 - mu) * rs * g[t      ] + bt[t      ]);
    d[t + 256] = (bf16_t)((v1 - mu) * rs * g[t + 256] + bt[t + 256]);
    d[t + 512] = (bf16_t)((v2 - mu) * rs * g[t + 512] + bt[t + 512]);
}

// ---------------- GEMM: C[M][N] = A[M][K] * W[N][K]^T, bf16 in, fp32 acc ----------------
template <int EPI>
__global__ __launch_bounds__(256)
void gemm_bt(const bf16_t* __restrict__ A, const bf16_t* __restrict__ W,
             const int K, const int N, const int KT,
             bf16_t* __restrict__ outB, float* __restrict__ outF,
             const float* __restrict__ bias, const float* __restrict__ resid,
             const int Mv)
{
    __shared__ bf16_t As[128 * 64];
    __shared__ bf16_t Bs[128 * 64];
    const int t = threadIdx.x;
    const int l = t & 63, w = t >> 6;
    const int lg = l >> 4, lc = l & 15;
    const int wr = w >> 1, wc = w & 1;
    const int nwg = gridDim.x * gridDim.y;
    const int orig = blockIdx.y * gridDim.x + blockIdx.x;
    const int wg = xcd_swz(orig, nwg);
    const int tileRow = (wg / gridDim.y) * 128;
    const int tileCol = (wg % gridDim.y) * 128;
    const int srow = l >> 3, scol = (l & 7) * 8;

    f32x4 acc[4][4];
#pragma unroll
    for (int i = 0; i < 4; ++i)
#pragma unroll
        for (int j = 0; j < 4; ++j) acc[i][j] = f32x4{0.f, 0.f, 0.f, 0.f};

    for (int kt = 0; kt < KT; ++kt) {
        const int k0 = kt * 64;
#pragma unroll
        for (int i = 0; i < 4; ++i) {
            const int c = w * 4 + i;
            gload16(&A[(size_t)(tileRow + c * 8 + srow) * K + k0 + scol], &As[c * 512]);
            gload16(&W[(size_t)(tileCol + c * 8 + srow) * K + k0 + scol], &Bs[c * 512]);
        }
        __syncthreads();
#pragma unroll
        for (int ks = 0; ks < 64; ks += 32) {
            bf16x8 af[4], bfv[4];
#pragma unroll
            for (int f = 0; f < 4; ++f)
                af[f] = *(const bf16x8*)&As[(wr * 64 + f * 16 + lc) * 64 + ks + 8 * lg];
#pragma unroll
            for (int f = 0; f < 4; ++f)
                bfv[f] = *(const bf16x8*)&Bs[(wc * 64 + f * 16 + lc) * 64 + ks + 8 * lg];
#pragma unroll
            for (int i = 0; i < 4; ++i)
#pragma unroll
                for (int j = 0; j < 4; ++j)
                    acc[i][j] = mfma16(af[i], bfv[j], acc[i][j]);
        }
        __syncthreads();
    }

    const int rowB = tileRow + wr * 64 + 4 * lg;
    const int colB = tileCol + wc * 64 + lc;
#pragma unroll
    for (int i = 0; i < 4; ++i) {
#pragma unroll
        for (int j = 0; j < 4; ++j) {
#pragma unroll
            for (int r = 0; r < 4; ++r) {
                const int row = rowB + i * 16 + r;
                const int col = colB + j * 16;
                float v = acc[i][j][r];
                if (EPI == 0) {
                    outB[(size_t)row * N + col] = (bf16_t)v;
                } else if (EPI == 1) {
                    const float xin = (row < Mv) ? resid[(size_t)row * N + col] : 0.f;
                    outF[(size_t)row * N + col] = v + xin;
                } else if (EPI == 2) {
                    v += bias[col];
                    v = 0.5f * v * (1.f + erff(v * 0.70710678118654752f));
                    outB[(size_t)row * N + col] = (bf16_t)v;
                } else {
                    if (row < Mv)
                        outF[(size_t)row * N + col] = v + bias[col] + resid[(size_t)row * N + col];
                }
            }
        }
    }
}

// ---------------- V transpose: qkv v-cols -> vt[(b*12+h)*64+e][n] (pad n zeroed) -----
__global__ __launch_bounds__(256)
void vtrans_kernel(const bf16_t* __restrict__ qkv, bf16_t* __restrict__ vt)
{
    const int nt = blockIdx.x, h = blockIdx.y, b = blockIdx.z;
    const int t = threadIdx.x;
    __shared__ bf16_t T[64][72];
    {
        const int nl = t >> 2, e0 = (t & 3) * 16;
        const int n = nt * 64 + nl;
        bf16x8 a, c;
        if (n < SEQ) {
            const bf16_t* src = &qkv[((size_t)b * SEQ + n) * QKVSTR + 1536 + h * EDIM + e0];
            a = *(const bf16x8*)src;
            c = *(const bf16x8*)(src + 8);
        } else {
#pragma unroll
            for (int u = 0; u < 8; ++u) { a[u] = (bf16_t)0.f; c[u] = (bf16_t)0.f; }
        }
#pragma unroll
        for (int u = 0; u < 8; ++u) { T[e0 + u][nl] = a[u]; T[e0 + 8 + u][nl] = c[u]; }
    }
    __syncthreads();
    {
        const int e = t >> 2, n0 = (t & 3) * 16;
        bf16x8 a, c;
#pragma unroll
        for (int u = 0; u < 8; ++u) { a[u] = T[e][n0 + u]; c[u] = T[e][n0 + 8 + u]; }
        bf16_t* d = &vt[((size_t)(b * NH + h) * EDIM + e) * NPAD + nt * 64 + n0];
        *(bf16x8*)d = a;
        *(bf16x8*)(d + 8) = c;
    }
}

// ---------------- differential flash attention v3 ----------------
// Swapped-operand MFMA: P and O^T live in lane layout col=q=lc.
// Softmax state per-lane scalar. P fragments built in-register via
// cvt_pk_bf16 + permlane{16,32}_swap (no P LDS roundtrip).
__global__ __launch_bounds__(256, 3)
void attn_kernel(const bf16_t* __restrict__ qkv, const bf16_t* __restrict__ vtp,
                 const float* __restrict__ lamp, const float* __restrict__ subg,
                 bf16_t* __restrict__ outp)
{
    const int orig = blockIdx.x + 5 * (blockIdx.y + 12 * blockIdx.z);
    const int wg = xcd_swz(orig, 1920);
    const int qt = wg % 5;
    const int h  = (wg / 5) % 12;
    const int b  = wg / 60;
    const int t = threadIdx.x, w = t >> 6, l = t & 63;
    const int lg = l >> 4, lc = l & 15;
    const float lam = *lamp;
    const float SC2 = 0.25503487f;       // (1/sqrt(32)) * log2(e)
    const float THR = 31.36f;            // 8 / SC2  (defer-max threshold, raw domain)

    __shared__ bf16_t Ks[2][64 * 64];
    __shared__ bf16_t Vs[2][64 * 64];

    const size_t mb = (size_t)b * SEQ;
    const int q0row = qt * 128 + w * 32;

    // Q fragments (B-operand of swapped QK): B[n=q=lc][d=8lg+j]
    bf16x8 qf[2][2];
#pragma unroll
    for (int qs = 0; qs < 2; ++qs)
#pragma unroll
        for (int hh = 0; hh < 2; ++hh)
            qf[qs][hh] = *(const bf16x8*)&qkv[(mb + q0row + qs * 16 + lc) * QKVSTR
                                              + h * 64 + hh * 32 + 8 * lg];

    // O^T accumulators: O[qs][hh][ef][r] = O[e=ef*16+4lg+r][q=lc]
    f32x4 O[2][2][4];
    f32x4 Ol[2][2];
    float mx[2][2];
#pragma unroll
    for (int qs = 0; qs < 2; ++qs)
#pragma unroll
        for (int hh = 0; hh < 2; ++hh) {
            Ol[qs][hh] = f32x4{0.f, 0.f, 0.f, 0.f};
#pragma unroll
            for (int ef = 0; ef < 4; ++ef) O[qs][hh][ef] = f32x4{0.f, 0.f, 0.f, 0.f};
            mx[qs][hh] = -3e38f;
        }

    bf16x8 ones;
#pragma unroll
    for (int u = 0; u < 8; ++u) ones[u] = (bf16_t)1.0f;

    // staging pointers (inverse-swizzled global source, linear LDS dest)
    const int lrow = l >> 3, lchunk = l & 7;
    const int scsw = (lchunk ^ (lrow & 7)) * 8;
    const bf16_t* kg[2];
    const bf16_t* vg[2];
#pragma unroll
    for (int ii = 0; ii < 2; ++ii) {
        const int row = w * 16 + ii * 8 + lrow;
        kg[ii] = &qkv[(mb + row) * QKVSTR + 768 + h * 64 + scsw];
        vg[ii] = &vtp[(size_t)((b * NH + h) * EDIM + row) * NPAD + scsw];
    }

    auto stage = [&](int kt, int bufi) {
#pragma unroll
        for (int ii = 0; ii < 2; ++ii) {
            const int R = (w * 16 + ii * 8) * 64;
            gload16(kg[ii] + (size_t)kt * (64 * QKVSTR), &Ks[bufi][R]);
            gload16(vg[ii] + kt * 64, &Vs[bufi][R]);
        }
    };

    stage(0, 0);
    int buf = 0;

    // precomputed swizzled LDS read offsets (elements)
    const int swz = lc & 7;
    int koff[2], voff[2];
#pragma unroll
    for (int hh = 0; hh < 2; ++hh) koff[hh] = lc * 64 + (((hh * 4 + lg) ^ swz) * 8);
#pragma unroll
    for (int ks = 0; ks < 2; ++ks) voff[ks] = lc * 64 + (((ks * 4 + lg) ^ swz) * 8);

#pragma unroll 1
    for (int kt = 0; kt < 10; ++kt) {
        __syncthreads();
        if (kt < 9) stage(kt + 1, buf ^ 1);

        const bf16_t* Kb = &Ks[buf][0];
        const bf16_t* Vb = &Vs[buf][0];
        // V^T fragments (A-operand of swapped PV): A[m=e=lc][k=8lg+j]
        bf16x8 vb[4][2];
#pragma unroll
        for (int ef = 0; ef < 4; ++ef)
#pragma unroll
            for (int ks = 0; ks < 2; ++ks)
                vb[ef][ks] = *(const bf16x8*)&Vb[voff[ks] + ef * 1024];

#pragma unroll
        for (int hh = 0; hh < 2; ++hh) {
            // K fragments (A-operand of swapped QK): A[m=krow=lc][d=8lg+j]
            bf16x8 kf[4];
#pragma unroll
            for (int f = 0; f < 4; ++f)
                kf[f] = *(const bf16x8*)&Kb[koff[hh] + f * 1024];
#pragma unroll
            for (int qs = 0; qs < 2; ++qs) {
                // s[f][r] = S[k = kt*64+16f+4lg+r][q = lc]
                f32x4 s[4];
#pragma unroll
                for (int f = 0; f < 4; ++f)
                    s[f] = mfma16(kf[f], qf[qs][hh], f32x4{0.f, 0.f, 0.f, 0.f});
                if (kt == 9) {
                    // only k=576 (f=0,lg=0,r=0) is valid
#pragma unroll
                    for (int f = 0; f < 4; ++f)
#pragma unroll
                        for (int r = 0; r < 4; ++r)
                            if (f | r) s[f][r] = -3e38f;
                    if (lg != 0) s[0][0] = -3e38f;
                }
                // row max: in-lane 16 then cross-lg
                float tm0 = fmaxf(fmaxf(s[0][0], s[0][1]), fmaxf(s[0][2], s[0][3]));
                float tm1 = fmaxf(fmaxf(s[1][0], s[1][1]), fmaxf(s[1][2], s[1][3]));
                float tm2 = fmaxf(fmaxf(s[2][0], s[2][1]), fmaxf(s[2][2], s[2][3]));
                float tm3 = fmaxf(fmaxf(s[3][0], s[3][1]), fmaxf(s[3][2], s[3][3]));
                float tm = fmaxf(fmaxf(tm0, tm1), fmaxf(tm2, tm3));
                tm = fmaxf(tm, __shfl_xor(tm, 16));
                tm = fmaxf(tm, __shfl_xor(tm, 32));
                float& m = mx[qs][hh];
                if (!__all(tm - m <= THR)) {       // defer-max (T13)
                    const float mn = fmaxf(m, tm);
                    const float al = __builtin_amdgcn_exp2f((m - mn) * SC2);
                    f32x4* Oc = O[qs][hh];
#pragma unroll
                    for (int ef = 0; ef < 4; ++ef)
#pragma unroll
                        for (int r = 0; r < 4; ++r) Oc[ef][r] *= al;
#pragma unroll
                    for (int r = 0; r < 4; ++r) Ol[qs][hh][r] *= al;
                    m = mn;
                }
                const float marg = m * SC2;
                // p = 2^(s*SC2 - marg), pack pairs along k (in-lane adjacent)
                unsigned wd[4][2];
#pragma unroll
                for (int f = 0; f < 4; ++f) {
                    float p0 = __builtin_amdgcn_exp2f(__builtin_fmaf(s[f][0], SC2, -marg));
                    float p1 = __builtin_amdgcn_exp2f(__builtin_fmaf(s[f][1], SC2, -marg));
                    float p2 = __builtin_amdgcn_exp2f(__builtin_fmaf(s[f][2], SC2, -marg));
                    float p3 = __builtin_amdgcn_exp2f(__builtin_fmaf(s[f][3], SC2, -marg));
                    wd[f][0] = cvt_pk_bf16(p0, p1);
                    wd[f][1] = cvt_pk_bf16(p2, p3);
                }
                // 4x4 lane-group transpose: (w00,w10)->j0,j2 ; (w01,w11)->j1,j3
#pragma unroll
                for (int half = 0; half < 2; ++half) {
#pragma unroll
                    for (int p = 0; p < 2; ++p) {
                        unsigned& A = wd[half * 2][p];
                        unsigned& B = wd[half * 2 + 1][p];
                        plane32_swap(A, B);
                        plane16_swap(A, B);
                    }
                }
                // B-operand P fragments: B[n=q=lc][kk=8lg+j]
                const bf16x8 pa0 = __builtin_bit_cast(bf16x8,
                    int4v{(int)wd[0][0], (int)wd[0][1], (int)wd[1][0], (int)wd[1][1]});
                const bf16x8 pa1 = __builtin_bit_cast(bf16x8,
                    int4v{(int)wd[2][0], (int)wd[2][1], (int)wd[3][0], (int)wd[3][1]});

                f32x4* Oc = O[qs][hh];
#pragma unroll
                for (int ef = 0; ef < 4; ++ef) {
                    Oc[ef] = mfma16(vb[ef][0], pa0, Oc[ef]);
                    Oc[ef] = mfma16(vb[ef][1], pa1, Oc[ef]);
                }
                Ol[qs][hh] = mfma16(ones, pa0, Ol[qs][hh]);
                Ol[qs][hh] = mfma16(ones, pa1, Ol[qs][hh]);
            }
        }
        buf ^= 1;
    }

    // epilogue: all lane-local (q=lc), rmsnorm over e via 2 shfl
#pragma unroll
    for (int qs = 0; qs < 2; ++qs) {
        const float i0 = 1.f / Ol[qs][0][0];
        const float i1 = lam / Ol[qs][1][0];
        float comb[4][4];
        float ms = 0.f;
#pragma unroll
        for (int ef = 0; ef < 4; ++ef)
#pragma unroll
            for (int r = 0; r < 4; ++r) {
                const float o = O[qs][0][ef][r] * i0 - O[qs][1][ef][r] * i1;
                comb[ef][r] = o;
                ms += o * o;
            }
        ms += __shfl_xor(ms, 16);
        ms += __shfl_xor(ms, 32);
        const float sc = rsqrtf(ms * (1.f / 64.f) + 1e-5f) * 0.8f;
        const int nq = q0row + qs * 16 + lc;
        if (nq < SEQ) {
            bf16_t* dst = &outp[(mb + nq) * DMODEL + h * EDIM + 4 * lg];
#pragma unroll
            for (int ef = 0; ef < 4; ++ef) {
                const f32x4 g4 = *(const f32x4*)&subg[ef * 16 + 4 * lg];
                const unsigned u0 = cvt_pk_bf16(comb[ef][0] * sc * g4[0],
                                                comb[ef][1] * sc * g4[1]);
                const unsigned u1 = cvt_pk_bf16(comb[ef][2] * sc * g4[2],
                                                comb[ef][3] * sc * g4[3]);
                *(uintx2*)(dst + ef * 16) = uintx2{u0, u1};
            }
        }
    }
}

// ---------------- launch ----------------
extern "C" void kernel_launch(void* const* d_in, const int* in_sizes, int n_in,
                              void* d_out, int out_size, void* d_ws, size_t ws_size,
                              hipStream_t stream)
{
    const float* x    = (const float*)d_in[0];
    const float* ln1g = (const float*)d_in[1];
    const float* ln1b = (const float*)d_in[2];
    const float* wq   = (const float*)d_in[3];
    const float* wk   = (const float*)d_in[4];
    const float* wv   = (const float*)d_in[5];
    const float* wo   = (const float*)d_in[6];
    const float* lq1  = (const float*)d_in[7];
    const float* lk1  = (const float*)d_in[8];
    const float* lq2  = (const float*)d_in[9];
    const float* lk2  = (const float*)d_in[10];
    const float* subg = (const float*)d_in[11];
    const float* ln2g = (const float*)d_in[12];
    const float* ln2b = (const float*)d_in[13];
    const float* w1   = (const float*)d_in[14];
    const float* b1   = (const float*)d_in[15];
    const float* w2   = (const float*)d_in[16];
    const float* b2   = (const float*)d_in[17];

    char* ws = (char*)d_ws;
    bf16_t* wAll = (bf16_t*)ws;               // wq|wk|wv (fused) | wo | w1 | w2
    bf16_t* wob = wAll + 1769472;
    bf16_t* w1b = wAll + 2359296;
    bf16_t* w2b = wAll + 4718592;
    ws += 7077888ull * 2;
    float* lamP = (float*)ws; ws += 256;
    bf16_t* xn   = (bf16_t*)ws; ws += (size_t)MPAD * DMODEL * 2;
    bf16_t* qkvb = (bf16_t*)ws;               // [MPAD][2304]; h1 aliases here later
    bf16_t* h1   = qkvb;
    ws += (size_t)MPAD * QKVSTR * 2;
    bf16_t* vtb  = (bf16_t*)ws; ws += (size_t)(BATCH * NH) * EDIM * NPAD * 2;
    bf16_t* aout = (bf16_t*)ws; ws += (size_t)MPAD * DMODEL * 2;
    float* x1    = (float*)ws;  ws += (size_t)MPAD * DMODEL * 4;

    wconv_kernel<<<6912, 256, 0, stream>>>(wq, wk, wv, wo, w1, w2, wAll);
    lam_kernel<<<1, 64, 0, stream>>>(lq1, lk1, lq2, lk2, lamP);
    ln_kernel<<<MPAD, 256, 0, stream>>>(x, ln1g, ln1b, xn, MROWS);

    // fused QKV: [MPAD][768] x [2304][768]^T
    gemm_bt<0><<<dim3(145, 18), 256, 0, stream>>>(xn, wAll, 768, QKVSTR, 12,
                                                  qkvb, nullptr, nullptr, nullptr, MROWS);

    vtrans_kernel<<<dim3(10, 12, 32), 256, 0, stream>>>(qkvb, vtb);
    attn_kernel<<<dim3(5, 12, 32), 256, 0, stream>>>(qkvb, vtb, lamP, subg, aout);

    gemm_bt<1><<<dim3(145, 6), 256, 0, stream>>>(aout, wob, 768, 768, 12,
                                                 nullptr, x1, nullptr, x, MROWS);
    ln_kernel<<<MPAD, 256, 0, stream>>>(x1, ln2g, ln2b, xn, MROWS);
    gemm_bt<2><<<dim3(145, 24), 256, 0, stream>>>(xn, w1b, 768, MLPD, 12,
                                                  h1, nullptr, b1, nullptr, MROWS);
    gemm_bt<3><<<dim3(145, 6), 256, 0, stream>>>(h1, w2b, MLPD, 768, 48,
                                                 nullptr, (float*)d_out, b2, x1, MROWS);
}